// Round 8
// baseline (376.683 us; speedup 1.0000x reference)
//
#include <hip/hip_runtime.h>
#include <math.h>

// LinearAttention — all GEMMs bf16 MFMA 16x16x32, fragment loads direct from
// global where layout permits (coalesced 64B lines via 4 quads x 16B).
//
// R1: k1 split into q-pass (32 AGPR) then kv-pass (64 AGPR), (256,4).
// R2: part f32 -> bf16.  total 369.
// R3: FAILED (reg-prefetch spilled at 128-reg cap).
// R4: FAILED ((256,3) no payload residency, cost occupancy).
// R5: FAILED (k3 128-px quarters: 4x attnT LDS re-reads).
// R7: float4 staging = neutral (reg-staged MLP exhausted: R2/R4/R7 all ~109).
//     k4 folded into k5. total 366.7 champion.
// R8: k1 staging via __builtin_amdgcn_global_load_lds (async DMA, zero reg
//     payload): 16 stages x 1KB/wave into 2x4KB raw ping-pong, counted
//     vmcnt(1), barrier-free (per-wave slices), LDS->LDS convert into the
//     unchanged swizzled xT. LDS 40KB -> still 4 blocks/CU.
//
// ws layout (float units):
//   q_wsT   @ 0         : bf16[32*4096*128]  [b][px][ch] softmaxed*SCALE q   (8388608 f)
//   wqkv_bf @ 8388608   : bf16[384*256]      row-major                      (49152 f)
//   wout_bf @ 8437760   : bf16[256*128]      row-major                      (16384 f)
//   ctxT_bf @ 8454144   : bf16[32*4*32*32]   [b][h][e][d] (transposed)      (65536 f)
//   part    @ 16777216  : bf16[2048][4096]   per-block context partials     (4194304 f)
//   gstats  @ 25165824  : f32 [128]

#define NPIX 4096
#define SCALE 0.17677669529663687f

typedef __bf16 bf16;
typedef __bf16 bf16x4 __attribute__((ext_vector_type(4)));
typedef __bf16 bf16x8 __attribute__((ext_vector_type(8)));
typedef float  f32x4  __attribute__((ext_vector_type(4)));

// ---------------------------------------------------------------------------
__global__ __launch_bounds__(256) void k0_convert(
    const float* __restrict__ Wqkv, const float* __restrict__ Wout,
    bf16* __restrict__ wqkv_bf, bf16* __restrict__ wout_bf)
{
    int i = blockIdx.x * 256 + threadIdx.x;   // < 131072
    if (i < 98304) wqkv_bf[i] = (bf16)Wqkv[i];
    else           wout_bf[i - 98304] = (bf16)Wout[i - 98304];
}

// ---------------------------------------------------------------------------
// k1: block = (batch b, 64-px tile). 4 waves, wave s = head s.
// qkv[384,64] = Wqkv x x. A-frags direct from global bf16 Wqkv (L2-hot).
// B-frags from LDS xT (transposed, XOR-swizzled). Barrier-free K-loop.
// Staging (R8): async DMA. Stage st (0..15) covers ch-rows st*16..+15 in
// natural [ch][px] f32; wave s DMAs its 4 rows (1 KB) into raw[st&1][s],
// waits vmcnt(1) (next stage already in flight), converts its own slice to
// the swizzled bf16 xT. No barriers until the single pre-GEMM barrier.
// LDS: xT 32 KB + raw 2x4 KB = 40960 B; overlay phase2: k/v 36864 B.
// ---------------------------------------------------------------------------
__global__ __launch_bounds__(256, 4) void k1_qkv(
    const float* __restrict__ x, const bf16* __restrict__ wqkv_bf,
    const float* __restrict__ bqkv, bf16* __restrict__ q_wsT,
    bf16* __restrict__ part)
{
    __shared__ __align__(16) bf16 sm[20480];   // 40960 B
    bf16* xT   = sm;                            // [px][256ch] bf16, swizzled, 32 KB
    char* rawb = (char*)sm + 32768;             // 2 x 4 KB f32 ping-pong

    const int blk  = blockIdx.x;
    const int b    = blk >> 6;
    const int n0   = (blk & 63) << 6;
    const int tid  = threadIdx.x;
    const int lane = tid & 63;
    const int s    = __builtin_amdgcn_readfirstlane(tid >> 6);
    const int m16  = lane & 15;
    const int quad = lane >> 4;

    const float* xb = x + (size_t)b * (256 * NPIX) + n0;

    // one 1KB DMA: lane covers (ch = ST*16 + s*4 + (lane>>4), px = (lane&15)*4..+3)
    // LDS dest is wave-uniform; HW adds lane*16 (linear slice).
#define STAGE_ISSUE(ST) do {                                                      \
        const float* gsrc = xb + (size_t)((ST)*16 + s*4 + (lane >> 4)) * NPIX     \
                               + (lane & 15) * 4;                                 \
        char* ldst = rawb + (((ST) & 1) * 4096 + s * 1024);                       \
        __builtin_amdgcn_global_load_lds(                                         \
            (const __attribute__((address_space(1))) void*)gsrc,                  \
            (__attribute__((address_space(3))) void*)ldst, 16, 0, 0);             \
    } while (0)

    STAGE_ISSUE(0);
    #pragma unroll
    for (int st = 0; st < 16; ++st) {
        __builtin_amdgcn_sched_barrier(0);
        if (st < 15) STAGE_ISSUE(st + 1);
        __builtin_amdgcn_sched_barrier(0);
        if (st < 15) asm volatile("s_waitcnt vmcnt(1)" ::: "memory");
        else         asm volatile("s_waitcnt vmcnt(0)" ::: "memory");
        __builtin_amdgcn_sched_barrier(0);
        // convert this wave's 4 ch-rows: column-wise reads (2-way bank = free)
        const float* rbuf = (const float*)(rawb + (st & 1) * 4096) + s * 256;
        float c0 = rbuf[0 * 64 + lane];
        float c1 = rbuf[1 * 64 + lane];
        float c2 = rbuf[2 * 64 + lane];
        float c3 = rbuf[3 * 64 + lane];
        int cq = st * 4 + s;            // ch-quad 0..63
        int g  = cq >> 1;
        int o  = (cq & 1) * 4;
        int px = lane;
        int gp = g ^ (px & 7);
        bf16x4 pk = { (bf16)c0, (bf16)c1, (bf16)c2, (bf16)c3 };
        *(bf16x4*)&xT[px * 256 + gp * 8 + o] = pk;
    }
#undef STAGE_ISSUE
    __syncthreads();

    // ---- pass 1: q GEMM (rows s*32 .. s*32+31), softmax over d, store q_wsT
    {
        f32x4 qacc[2][4] = {};
        for (int kc = 0; kc < 8; ++kc) {
            bf16x8 bfr[4];
            #pragma unroll
            for (int nt = 0; nt < 4; ++nt) {
                int px = nt*16 + m16;
                int gp = (kc*4 + quad) ^ (px & 7);
                bfr[nt] = *(const bf16x8*)&xT[px*256 + gp*8];
            }
            #pragma unroll
            for (int mt = 0; mt < 2; ++mt) {
                int row = s*32 + mt*16 + m16;
                bf16x8 afr = *(const bf16x8*)&wqkv_bf[(size_t)row*256 + kc*32 + quad*8];
                #pragma unroll
                for (int nt = 0; nt < 4; ++nt)
                    qacc[mt][nt] = __builtin_amdgcn_mfma_f32_16x16x32_bf16(afr, bfr[nt], qacc[mt][nt], 0, 0, 0);
            }
        }
        float bq[8];
        #pragma unroll
        for (int j = 0; j < 8; ++j)
            bq[j] = bqkv[s*32 + (j >> 2)*16 + quad*4 + (j & 3)];

        #pragma unroll
        for (int nt = 0; nt < 4; ++nt) {
            float v[8]; float mx = -1e30f;
            #pragma unroll
            for (int j = 0; j < 8; ++j) { v[j] = qacc[j>>2][nt][j&3] + bq[j]; mx = fmaxf(mx, v[j]); }
            mx = fmaxf(mx, __shfl_xor(mx, 16));
            mx = fmaxf(mx, __shfl_xor(mx, 32));
            float sum = 0.f;
            #pragma unroll
            for (int j = 0; j < 8; ++j) { v[j] = __expf(v[j] - mx); sum += v[j]; }
            sum += __shfl_xor(sum, 16);
            sum += __shfl_xor(sum, 32);
            float rs = SCALE / sum;
            size_t rowb = (size_t)(b*4096 + n0 + nt*16 + m16) * 128;
            #pragma unroll
            for (int mt = 0; mt < 2; ++mt) {
                bf16x4 pk = { (bf16)(v[mt*4+0]*rs), (bf16)(v[mt*4+1]*rs),
                              (bf16)(v[mt*4+2]*rs), (bf16)(v[mt*4+3]*rs) };
                *(bf16x4*)&q_wsT[rowb + s*32 + mt*16 + quad*4] = pk;
            }
        }
    }

    // ---- pass 2: k,v GEMM (rows 128+s*32.. and 256+s*32..)
    f32x4 acc[4][4] = {};   // m-tiles: k0,k1,v0,v1 ; 4 n-tiles
    for (int kc = 0; kc < 8; ++kc) {
        bf16x8 bfr[4];
        #pragma unroll
        for (int nt = 0; nt < 4; ++nt) {
            int px = nt*16 + m16;
            int gp = (kc*4 + quad) ^ (px & 7);
            bfr[nt] = *(const bf16x8*)&xT[px*256 + gp*8];
        }
        #pragma unroll
        for (int mt = 0; mt < 4; ++mt) {
            int row = 128 + (mt >> 1)*128 + s*32 + (mt & 1)*16 + m16;
            bf16x8 afr = *(const bf16x8*)&wqkv_bf[(size_t)row*256 + kc*32 + quad*8];
            #pragma unroll
            for (int nt = 0; nt < 4; ++nt)
                acc[mt][nt] = __builtin_amdgcn_mfma_f32_16x16x32_bf16(afr, bfr[nt], acc[mt][nt], 0, 0, 0);
        }
    }

    float bk[8], bv[8];
    #pragma unroll
    for (int j = 0; j < 8; ++j) {
        int rr = (j >> 2)*16 + quad*4 + (j & 3);
        bk[j] = bqkv[128 + s*32 + rr];
        bv[j] = bqkv[256 + s*32 + rr];
    }

    // k softmax + v bias -> LDS overlay (xT dead; barrier for WAR)
    __syncthreads();
    bf16* kl = sm + s*2304;          // [32][72]
    bf16* vl = sm + 9216 + s*2304;   // [32][72]
    #pragma unroll
    for (int nt = 0; nt < 4; ++nt) {
        float v[8]; float mx = -1e30f;
        #pragma unroll
        for (int j = 0; j < 8; ++j) { v[j] = acc[j>>2][nt][j&3] + bk[j]; mx = fmaxf(mx, v[j]); }
        mx = fmaxf(mx, __shfl_xor(mx, 16));
        mx = fmaxf(mx, __shfl_xor(mx, 32));
        float sum = 0.f;
        #pragma unroll
        for (int j = 0; j < 8; ++j) { v[j] = __expf(v[j] - mx); sum += v[j]; }
        sum += __shfl_xor(sum, 16);
        sum += __shfl_xor(sum, 32);
        float rs = 1.f / sum;
        #pragma unroll
        for (int j = 0; j < 8; ++j) {
            int d  = (j>>2)*16 + quad*4 + (j&3);
            int px = nt*16 + m16;
            kl[d*72 + px] = (bf16)(v[j] * rs);
            vl[d*72 + px] = (bf16)(acc[2 + (j>>2)][nt][j&3] + bv[j]);
        }
    }
    __syncthreads();

    // context partial: ctx[d][e] = sum_p k[d][p]*v[e][p]
    f32x4 cacc[2][2] = {};
    #pragma unroll
    for (int ks = 0; ks < 2; ++ks) {
        bf16x8 ak[2], bvv[2];
        #pragma unroll
        for (int mt = 0; mt < 2; ++mt)
            ak[mt] = *(const bf16x8*)&kl[(mt*16 + m16)*72 + ks*32 + quad*8];
        #pragma unroll
        for (int nt = 0; nt < 2; ++nt)
            bvv[nt] = *(const bf16x8*)&vl[(nt*16 + m16)*72 + ks*32 + quad*8];
        #pragma unroll
        for (int mt = 0; mt < 2; ++mt)
            #pragma unroll
            for (int nt = 0; nt < 2; ++nt)
                cacc[mt][nt] = __builtin_amdgcn_mfma_f32_16x16x32_bf16(ak[mt], bvv[nt], cacc[mt][nt], 0, 0, 0);
    }
    bf16* pdst = part + (size_t)blk * 4096 + s*1024;
    #pragma unroll
    for (int mt = 0; mt < 2; ++mt)
        #pragma unroll
        for (int nt = 0; nt < 2; ++nt)
            #pragma unroll
            for (int r = 0; r < 4; ++r)
                pdst[(mt*16 + quad*4 + r)*32 + nt*16 + m16] = (bf16)cacc[mt][nt][r];
}

// ---------------------------------------------------------------------------
__global__ __launch_bounds__(256) void k2_reduce(
    const bf16* __restrict__ part, bf16* __restrict__ ctxT_bf)
{
    int i = blockIdx.x * 256 + threadIdx.x;   // < 131072
    int b = i >> 12, r = i & 4095;
    const bf16* p = part + (size_t)b * 64 * 4096 + r;
    float sum = 0.f;
    #pragma unroll 8
    for (int j = 0; j < 64; ++j) sum += (float)p[(size_t)j * 4096];
    int h = r >> 10, d = (r >> 5) & 31, e = r & 31;
    ctxT_bf[(size_t)((b*4 + h)*32 + e)*32 + d] = (bf16)sum;   // transposed
}

// ---------------------------------------------------------------------------
// k3: block = (b, 64-px tile). Wave s: attn for head s, then out rows s*64..+63.
// (R2-exact body — the R4/R5 splits regressed; single-pass 4x4 acc is best.)
// ---------------------------------------------------------------------------
__global__ __launch_bounds__(256) void k3_out(
    const bf16* __restrict__ q_wsT, const bf16* __restrict__ ctxT_bf,
    const bf16* __restrict__ wout_bf, const float* __restrict__ bout,
    float* __restrict__ out, float* __restrict__ gstats)
{
    __shared__ __align__(16) bf16 attnT[8192];
    __shared__ float red[512];
    const int blk  = blockIdx.x;
    const int b    = blk >> 6;
    const int n0   = (blk & 63) << 6;
    const int tid  = threadIdx.x;
    const int lane = tid & 63;
    const int s    = __builtin_amdgcn_readfirstlane(tid >> 6);
    const int m16  = lane & 15;
    const int quad = lane >> 4;

    // ---- attn GEMM (head s): A = ctxT[b][s][e][d], B^T = q_wsT[b][px][s*32+d]
    f32x4 aacc[2][4] = {};
    {
        bf16x8 afr[2], bfr[4];
        const bf16* ctxs = ctxT_bf + (size_t)(b*4 + s) * 1024;
        #pragma unroll
        for (int mt = 0; mt < 2; ++mt)
            afr[mt] = *(const bf16x8*)&ctxs[(mt*16 + m16)*32 + quad*8];
        const bf16* qb = q_wsT + (size_t)(b*4096 + n0) * 128 + s*32;
        #pragma unroll
        for (int nt = 0; nt < 4; ++nt)
            bfr[nt] = *(const bf16x8*)&qb[(size_t)(nt*16 + m16)*128 + quad*8];
        #pragma unroll
        for (int mt = 0; mt < 2; ++mt)
            #pragma unroll
            for (int nt = 0; nt < 4; ++nt)
                aacc[mt][nt] = __builtin_amdgcn_mfma_f32_16x16x32_bf16(afr[mt], bfr[nt], aacc[mt][nt], 0, 0, 0);
    }

    // write attnT[p][ch] swizzled: gp = (ch>>3) ^ (p&15)
    #pragma unroll
    for (int mt = 0; mt < 2; ++mt)
        #pragma unroll
        for (int nt = 0; nt < 4; ++nt) {
            int p   = nt*16 + m16;
            int chb = s*32 + mt*16 + quad*4;
            int gp  = (chb >> 3) ^ m16;
            bf16x4 pk = { (bf16)aacc[mt][nt][0], (bf16)aacc[mt][nt][1],
                          (bf16)aacc[mt][nt][2], (bf16)aacc[mt][nt][3] };
            *(bf16x4*)&attnT[p*128 + gp*8 + (quad & 1)*4] = pk;
        }
    __syncthreads();

    // ---- Wout GEMM: rows o = s*64 + mt*16 + m16, K = 128 (4 chunks)
    f32x4 acc[4][4] = {};
    const bf16* wb = wout_bf + (size_t)s * 64 * 128;
    for (int kc = 0; kc < 4; ++kc) {
        bf16x8 wfr[4], xfr[4];
        #pragma unroll
        for (int mt = 0; mt < 4; ++mt)
            wfr[mt] = *(const bf16x8*)&wb[(size_t)(mt*16 + m16)*128 + kc*32 + quad*8];
        #pragma unroll
        for (int nt = 0; nt < 4; ++nt) {
            int p  = nt*16 + m16;
            int gp = (kc*4 + quad) ^ m16;
            xfr[nt] = *(const bf16x8*)&attnT[p*128 + gp*8];
        }
        #pragma unroll
        for (int mt = 0; mt < 4; ++mt)
            #pragma unroll
            for (int nt = 0; nt < 4; ++nt)
                acc[mt][nt] = __builtin_amdgcn_mfma_f32_16x16x32_bf16(wfr[mt], xfr[nt], acc[mt][nt], 0, 0, 0);
    }

    // epilogue: bias, coalesced f32 stores, per-lane stats
    float ls = 0.f, lss = 0.f;
    float* ob = out + ((size_t)b*256 + s*64) * NPIX + n0;
    #pragma unroll
    for (int mt = 0; mt < 4; ++mt) {
        #pragma unroll
        for (int r = 0; r < 4; ++r) {
            int o = mt*16 + quad*4 + r;
            float bo = bout[s*64 + o];
            #pragma unroll
            for (int nt = 0; nt < 4; ++nt) {
                float v = acc[mt][nt][r] + bo;
                ob[(size_t)o*NPIX + nt*16 + m16] = v;
                ls += v; lss += v*v;
            }
        }
    }

    red[tid] = ls; red[256 + tid] = lss;
    __syncthreads();
    for (int off = 128; off > 0; off >>= 1) {
        if (tid < off) {
            red[tid]       += red[tid + off];
            red[256 + tid] += red[256 + tid + off];
        }
        __syncthreads();
    }
    if (tid == 0) {
        atomicAdd(&gstats[b],      red[0]);
        atomicAdd(&gstats[32 + b], red[256]);
    }
}

// ---------------------------------------------------------------------------
// k5: GroupNorm apply (k4 folded in: mean/rsqrt derived from raw sums — two
// wave-uniform scalar loads). Same 32768-block one-shot shape as R2.
// ---------------------------------------------------------------------------
__global__ __launch_bounds__(256) void k5_norm(
    float* __restrict__ out, const float* __restrict__ gstats,
    const float* __restrict__ gamma, const float* __restrict__ beta)
{
    const float inv_cnt = 1.0f / 1048576.0f;   // 256*4096
    size_t gid  = (size_t)blockIdx.x * 256 + threadIdx.x;
    size_t base = gid * 4;
    int b = (int)(base >> 20);
    int o = (int)((base >> 12) & 255);
    float m   = gstats[b]      * inv_cnt;
    float var = gstats[32 + b] * inv_cnt - m*m;
    float inv = rsqrtf(var + 1e-5f);
    float a = inv * gamma[o];
    float c = beta[o] - m * a;
    float4 v = ((float4*)out)[gid];
    v.x = v.x * a + c; v.y = v.y * a + c;
    v.z = v.z * a + c; v.w = v.w * a + c;
    ((float4*)out)[gid] = v;
}

extern "C" void kernel_launch(void* const* d_in, const int* in_sizes, int n_in,
                              void* d_out, int out_size, void* d_ws, size_t ws_size,
                              hipStream_t stream) {
    const float* x     = (const float*)d_in[0];
    const float* Wqkv  = (const float*)d_in[1];
    const float* bqkv  = (const float*)d_in[2];
    const float* Wout  = (const float*)d_in[3];
    const float* bout  = (const float*)d_in[4];
    const float* gamma = (const float*)d_in[5];
    const float* beta  = (const float*)d_in[6];
    float* out = (float*)d_out;
    float* ws  = (float*)d_ws;

    bf16*  q_wsT   = (bf16*)ws;
    bf16*  wqkv_bf = (bf16*)(ws + 8388608);
    bf16*  wout_bf = (bf16*)(ws + 8437760);
    bf16*  ctxT_bf = (bf16*)(ws + 8454144);
    bf16*  part    = (bf16*)(ws + 16777216);
    float* gstats  = ws + 25165824;

    hipMemsetAsync(gstats, 0, 64 * sizeof(float), stream);
    k0_convert<<<512,  256, 0, stream>>>(Wqkv, Wout, wqkv_bf, wout_bf);
    k1_qkv    <<<2048, 256, 0, stream>>>(x, wqkv_bf, bqkv, q_wsT, part);
    k2_reduce <<<512,  256, 0, stream>>>(part, ctxT_bf);
    k3_out    <<<2048, 256, 0, stream>>>(q_wsT, ctxT_bf, wout_bf, bout, out, gstats);
    k5_norm   <<<32768,256, 0, stream>>>(out, gstats, gamma, beta);
}